// Round 1
// baseline (415.263 us; speedup 1.0000x reference)
//
#include <hip/hip_runtime.h>
#include <math.h>

// CentroidInstanceLoss: N=2M points, D=16, B=8 subbatches, M=32 labels.
// out = (L_pull + L_push)/B  (single fp32 scalar)
//
// R5: coalescing + MLP rewrite. R4 counters showed latency-bound (VALUBusy 3%,
// HBM 8%, occ 24%): 64B-per-lane stride (one wave load = 64 cachelines) plus a
// rolled loop (VGPR=28 -> one vmcnt(0) round trip per point). Now lane i owns a
// 16B slice (4 lanes per point, wave-contiguous loads), per-point reductions via
// 2x __shfl_xor, and 24 loads batched up front per round for MLP.

#define DD 16
#define MM 32
#define BBATCH 8
#define SEGS 256          // B*M
#define DELTA_V 0.5f
#define DELTA_D 1.5f
#define NEPS 1e-8f

#define NBLK 2048
#define NTHR 256
#define SLOTS_PER_BLK 4096   // float4-slots per block = 4*N/NBLK
#define UF 8                 // batched loads per round
#define ROUNDS (SLOTS_PER_BLK / (NTHR * UF))   // 2

// ws layout (floats):
//   [0,4096)        seg_sum   [seg][d]
//   [4096,4352)     seg_cnt   [seg]
//   [4352,8448)     mus       [seg][d]  (seg-major)
//   [8448,8704)     invw      [seg]   = 1/(M*count)
//   [8704]          push_acc
//   [8720,8720+NBLK) pull_part
#define WS_ZERO_FLOATS 4352

__device__ __forceinline__ void lds_fadd(float* p, float v) {
    __hip_atomic_fetch_add(p, v, __ATOMIC_RELAXED, __HIP_MEMORY_SCOPE_WORKGROUP);
}

__device__ __forceinline__ float block_reduce_sum(float v) {
    #pragma unroll
    for (int o = 32; o > 0; o >>= 1) v += __shfl_down(v, o, 64);
    __shared__ float red[4];
    int wid  = threadIdx.x >> 6;
    int lane = threadIdx.x & 63;
    if (lane == 0) red[wid] = v;
    __syncthreads();
    v = (threadIdx.x < (NTHR >> 6)) ? red[threadIdx.x] : 0.0f;
    if (wid == 0) {
        #pragma unroll
        for (int o = 32; o > 0; o >>= 1) v += __shfl_down(v, o, 64);
    }
    return v;  // valid on thread 0
}

// flush one lane's float4 slice accumulator into the transposed LDS planes
__device__ __forceinline__ void flush_slice(float* lsT, int seg, int j,
                                            float4 a, float cnt, bool cnt_lane) {
    lds_fadd(&lsT[(4*j + 0) * SEGS + seg], a.x);
    lds_fadd(&lsT[(4*j + 1) * SEGS + seg], a.y);
    lds_fadd(&lsT[(4*j + 2) * SEGS + seg], a.z);
    lds_fadd(&lsT[(4*j + 3) * SEGS + seg], a.w);
    if (cnt_lane) lds_fadd(&lsT[DD * SEGS + seg], cnt);
}

__global__ void __launch_bounds__(NTHR, 4)
k_segsum(const float4* __restrict__ o4,
         const int* __restrict__ labels,
         const int* __restrict__ sub,
         float* __restrict__ seg_sum,
         float* __restrict__ seg_cnt,
         int n) {
    __shared__ float lsT[(DD + 1) * SEGS];  // planes [d][seg]; plane 16 = count
    for (int i = threadIdx.x; i < (DD + 1) * SEGS; i += NTHR) lsT[i] = 0.0f;
    __syncthreads();

    const int t = threadIdx.x;
    const int j = t & 3;                 // slice index, loop-invariant (NTHR%4==0)
    const bool cnt_lane = (j == 0);
    const long nslot = 4L * (long)n;
    const long base  = (long)blockIdx.x * SLOTS_PER_BLK + t;

    float4 acc = {0, 0, 0, 0};
    float cnt = 0.0f;
    int cur = -1;

    const bool full = ((long)(blockIdx.x + 1) * SLOTS_PER_BLK) <= nslot;
    if (full) {
        #pragma unroll
        for (int r = 0; r < ROUNDS; ++r) {
            float4 v[UF]; int lb[UF], sb[UF];
            #pragma unroll
            for (int u = 0; u < UF; ++u) {
                int q = (int)base + (r * UF + u) * NTHR;
                v[u] = o4[q];
                int p = q >> 2;
                lb[u] = labels[p];
                sb[u] = sub[p];
            }
            #pragma unroll
            for (int u = 0; u < UF; ++u) {
                int seg = sb[u] * MM + lb[u];
                float ssp = v[u].x*v[u].x + v[u].y*v[u].y
                          + v[u].z*v[u].z + v[u].w*v[u].w;
                ssp += __shfl_xor(ssp, 1, 64);
                ssp += __shfl_xor(ssp, 2, 64);      // full |x|^2 on all 4 lanes
                float rn = 1.0f / (sqrtf(ssp) + NEPS);
                if (seg != cur) {                   // never fires for canonical input
                    if (cur >= 0) flush_slice(lsT, cur, j, acc, cnt, cnt_lane);
                    acc = (float4){0, 0, 0, 0};
                    cnt = 0.0f;
                    cur = seg;
                }
                acc.x = fmaf(v[u].x, rn, acc.x);
                acc.y = fmaf(v[u].y, rn, acc.y);
                acc.z = fmaf(v[u].z, rn, acc.z);
                acc.w = fmaf(v[u].w, rn, acc.w);
                cnt += 1.0f;
            }
        }
    } else {
        for (int k = 0; k < SLOTS_PER_BLK / NTHR; ++k) {
            long q = base + (long)k * NTHR;
            if (q >= nslot) break;
            float4 v = o4[q];
            int p = (int)(q >> 2);
            int seg = sub[p] * MM + labels[p];
            float ssp = v.x*v.x + v.y*v.y + v.z*v.z + v.w*v.w;
            ssp += __shfl_xor(ssp, 1, 64);
            ssp += __shfl_xor(ssp, 2, 64);
            float rn = 1.0f / (sqrtf(ssp) + NEPS);
            if (seg != cur) {
                if (cur >= 0) flush_slice(lsT, cur, j, acc, cnt, cnt_lane);
                acc = (float4){0, 0, 0, 0};
                cnt = 0.0f;
                cur = seg;
            }
            acc.x = fmaf(v.x, rn, acc.x);
            acc.y = fmaf(v.y, rn, acc.y);
            acc.z = fmaf(v.z, rn, acc.z);
            acc.w = fmaf(v.w, rn, acc.w);
            cnt += 1.0f;
        }
    }
    if (cur >= 0) flush_slice(lsT, cur, j, acc, cnt, cnt_lane);
    __syncthreads();

    // global flush: only segments this block actually touched (count != 0)
    for (int s = threadIdx.x; s < SEGS; s += NTHR) {
        float c = lsT[DD * SEGS + s];
        if (c != 0.0f) {
            #pragma unroll
            for (int d = 0; d < DD; ++d)
                unsafeAtomicAdd(&seg_sum[s * DD + d], lsT[d * SEGS + s]);
            unsafeAtomicAdd(&seg_cnt[s], c);
        }
    }
}

__global__ void k_finalize_push(float* __restrict__ ws) {
    const float* seg_sum = ws;
    const float* seg_cnt = ws + 4096;
    float* mus  = ws + 4352;
    float* invw = ws + 8448;
    float* push = ws + 8704;

    __shared__ float muT[DD * SEGS];
    int t = threadIdx.x;  // 256 threads == one per segment
    float cnt = seg_cnt[t];
    float ic  = (cnt > 0.0f) ? 1.0f / cnt : 0.0f;
    #pragma unroll
    for (int d = 0; d < DD; ++d) {
        float m = seg_sum[t * DD + d] * ic;
        mus[t * DD + d]   = m;
        muT[d * SEGS + t] = m;
    }
    invw[t] = (cnt > 0.0f) ? 1.0f / ((float)MM * cnt) : 0.0f;
    __syncthreads();

    int b = t >> 5, m1 = t & 31;
    float acc = 0.0f;
    for (int m2 = 0; m2 < MM; ++m2) {
        float pd = 0.0f;
        #pragma unroll
        for (int d = 0; d < DD; ++d)
            pd += fabsf(muT[d * SEGS + b * MM + m1] - muT[d * SEGS + b * MM + m2]);
        float h = 2.0f * DELTA_D - pd;
        if (m2 != m1 && h > 0.0f) acc += h * h;
    }
    float tot = block_reduce_sum(acc);
    if (t == 0) push[0] = tot / (float)(MM * (MM - 1));
}

__global__ void __launch_bounds__(NTHR, 4)
k_pull(const float4* __restrict__ o4,
       const int* __restrict__ labels,
       const int* __restrict__ sub,
       const float* __restrict__ mus,
       const float* __restrict__ invw,
       float* __restrict__ pull_part,
       int n) {
    __shared__ float muL[DD * SEGS];  // seg-major (matches ws mus layout)
    __shared__ float siw[SEGS];
    for (int i = threadIdx.x; i < DD * SEGS; i += NTHR) muL[i] = mus[i];
    for (int i = threadIdx.x; i < SEGS; i += NTHR) siw[i] = invw[i];
    __syncthreads();

    const int t = threadIdx.x;
    const int j = t & 3;
    const bool cnt_lane = (j == 0);
    const long nslot = 4L * (long)n;
    const long base  = (long)blockIdx.x * SLOTS_PER_BLK + t;

    float4 m = {0, 0, 0, 0};
    float iwl = 0.0f;        // masked: nonzero only on slice-0 lane
    int cur = -1;
    float acc = 0.0f;

    const bool full = ((long)(blockIdx.x + 1) * SLOTS_PER_BLK) <= nslot;
    if (full) {
        #pragma unroll
        for (int r = 0; r < ROUNDS; ++r) {
            float4 v[UF]; int lb[UF], sb[UF];
            #pragma unroll
            for (int u = 0; u < UF; ++u) {
                int q = (int)base + (r * UF + u) * NTHR;
                v[u] = o4[q];
                int p = q >> 2;
                lb[u] = labels[p];
                sb[u] = sub[p];
            }
            #pragma unroll
            for (int u = 0; u < UF; ++u) {
                int seg = sb[u] * MM + lb[u];
                if (seg != cur) {                  // once per thread for canonical input
                    cur = seg;
                    m = *(const float4*)&muL[seg * DD + 4 * j];
                    iwl = cnt_lane ? siw[seg] : 0.0f;
                }
                float ssp = v[u].x*v[u].x + v[u].y*v[u].y
                          + v[u].z*v[u].z + v[u].w*v[u].w;
                ssp += __shfl_xor(ssp, 1, 64);
                ssp += __shfl_xor(ssp, 2, 64);
                float rn = 1.0f / (sqrtf(ssp) + NEPS);
                float d = fabsf(m.x - v[u].x * rn) + fabsf(m.y - v[u].y * rn)
                        + fabsf(m.z - v[u].z * rn) + fabsf(m.w - v[u].w * rn);
                d += __shfl_xor(d, 1, 64);
                d += __shfl_xor(d, 2, 64);         // full L1 dist on all 4 lanes
                float h = d - DELTA_V;
                if (h > 0.0f) acc = fmaf(h * h, iwl, acc);
            }
        }
    } else {
        for (int k = 0; k < SLOTS_PER_BLK / NTHR; ++k) {
            long q = base + (long)k * NTHR;
            if (q >= nslot) break;
            float4 v = o4[q];
            int p = (int)(q >> 2);
            int seg = sub[p] * MM + labels[p];
            if (seg != cur) {
                cur = seg;
                m = *(const float4*)&muL[seg * DD + 4 * j];
                iwl = cnt_lane ? siw[seg] : 0.0f;
            }
            float ssp = v.x*v.x + v.y*v.y + v.z*v.z + v.w*v.w;
            ssp += __shfl_xor(ssp, 1, 64);
            ssp += __shfl_xor(ssp, 2, 64);
            float rn = 1.0f / (sqrtf(ssp) + NEPS);
            float d = fabsf(m.x - v.x * rn) + fabsf(m.y - v.y * rn)
                    + fabsf(m.z - v.z * rn) + fabsf(m.w - v.w * rn);
            d += __shfl_xor(d, 1, 64);
            d += __shfl_xor(d, 2, 64);
            float h = d - DELTA_V;
            if (h > 0.0f) acc = fmaf(h * h, iwl, acc);
        }
    }
    float tot = block_reduce_sum(acc);
    if (threadIdx.x == 0) pull_part[blockIdx.x] = tot;
}

__global__ void k_final(const float* __restrict__ ws, float* __restrict__ out) {
    const float* push      = ws + 8704;
    const float* pull_part = ws + 8720;
    int t = threadIdx.x;
    float v = 0.0f;
    #pragma unroll
    for (int k = 0; k < NBLK / NTHR; ++k) v += pull_part[t + k * NTHR];
    float tot = block_reduce_sum(v);
    if (t == 0) out[0] = (tot + push[0]) * (1.0f / (float)BBATCH);
}

extern "C" void kernel_launch(void* const* d_in, const int* in_sizes, int n_in,
                              void* d_out, int out_size, void* d_ws, size_t ws_size,
                              hipStream_t stream) {
    const float* outputs = (const float*)d_in[0];
    const int* labels    = (const int*)d_in[1];
    const int* sub       = (const int*)d_in[2];
    int n = in_sizes[0] / DD;

    float* ws        = (float*)d_ws;
    float* seg_sum   = ws;
    float* seg_cnt   = ws + 4096;
    float* mus       = ws + 4352;
    float* invw      = ws + 8448;
    float* pull_part = ws + 8720;

    hipMemsetAsync(d_ws, 0, WS_ZERO_FLOATS * sizeof(float), stream);

    k_segsum<<<NBLK, NTHR, 0, stream>>>((const float4*)outputs, labels, sub,
                                        seg_sum, seg_cnt, n);
    k_finalize_push<<<1, NTHR, 0, stream>>>(ws);
    k_pull<<<NBLK, NTHR, 0, stream>>>((const float4*)outputs, labels, sub,
                                      mus, invw, pull_part, n);
    k_final<<<1, NTHR, 0, stream>>>(ws, (float*)d_out);
}

// Round 2
// 393.382 us; speedup vs baseline: 1.0556x; 1.0556x over previous
//
#include <hip/hip_runtime.h>
#include <math.h>

// CentroidInstanceLoss: N=2M points, D=16, B=8 subbatches, M=32 labels.
// out = (L_pull + L_push)/B  (single fp32 scalar)
//
// R6: forced-MLP rewrite. R4/R5 counters: latency-bound (VALUBusy 3-4%, HBM
// 5-8%, bank conflicts 0). R5's batching failed (VGPR=36 proves the compiler
// sank the loads back into the consume loop -> serialized round trips).
// Now: point-per-lane layout (R4's, no shfl in the chain), PPT=4 points per
// thread, ONE batched round: 8 int loads + 16 float4 loads issued back-to-back,
// then __builtin_amdgcn_sched_barrier(0) pins them before any use -> the
// allocator must keep ~110 VGPRs of loads in flight. launch_bounds(256,3)
// raises the VGPR cap to ~168 so nothing spills.

#define DD 16
#define MM 32
#define BBATCH 8
#define SEGS 256          // B*M
#define DELTA_V 0.5f
#define DELTA_D 1.5f
#define NEPS 1e-8f

#define NTHR 256
#define PPT 4                 // points per thread, one batched round
#define CHUNK (NTHR * PPT)    // 1024 points per block; N/CHUNK = 2048 blocks
#define MAXBLK 4096           // pull_part capacity

// ws layout (floats):
//   [0,4096)        seg_sum   [seg][d]
//   [4096,4352)     seg_cnt   [seg]
//   [4352,8448)     mus       [seg][d]  (seg-major)
//   [8448,8704)     invw      [seg]   = 1/(M*count)
//   [8704]          push_acc
//   [8720,8720+nblk) pull_part
#define WS_ZERO_FLOATS 4352

__device__ __forceinline__ void lds_fadd(float* p, float v) {
    __hip_atomic_fetch_add(p, v, __ATOMIC_RELAXED, __HIP_MEMORY_SCOPE_WORKGROUP);
}

__device__ __forceinline__ float block_reduce_sum(float v) {
    #pragma unroll
    for (int o = 32; o > 0; o >>= 1) v += __shfl_down(v, o, 64);
    __shared__ float red[4];
    int wid  = threadIdx.x >> 6;
    int lane = threadIdx.x & 63;
    if (lane == 0) red[wid] = v;
    __syncthreads();
    v = (threadIdx.x < (NTHR >> 6)) ? red[threadIdx.x] : 0.0f;
    if (wid == 0) {
        #pragma unroll
        for (int o = 32; o > 0; o >>= 1) v += __shfl_down(v, o, 64);
    }
    return v;  // valid on thread 0
}

// flush a full-point accumulator (16 floats + count) into transposed LDS planes
__device__ __forceinline__ void flush_point(float* lsT, int seg,
                                            float4 a0, float4 a1,
                                            float4 a2, float4 a3, float cnt) {
    lds_fadd(&lsT[ 0*SEGS + seg], a0.x); lds_fadd(&lsT[ 1*SEGS + seg], a0.y);
    lds_fadd(&lsT[ 2*SEGS + seg], a0.z); lds_fadd(&lsT[ 3*SEGS + seg], a0.w);
    lds_fadd(&lsT[ 4*SEGS + seg], a1.x); lds_fadd(&lsT[ 5*SEGS + seg], a1.y);
    lds_fadd(&lsT[ 6*SEGS + seg], a1.z); lds_fadd(&lsT[ 7*SEGS + seg], a1.w);
    lds_fadd(&lsT[ 8*SEGS + seg], a2.x); lds_fadd(&lsT[ 9*SEGS + seg], a2.y);
    lds_fadd(&lsT[10*SEGS + seg], a2.z); lds_fadd(&lsT[11*SEGS + seg], a2.w);
    lds_fadd(&lsT[12*SEGS + seg], a3.x); lds_fadd(&lsT[13*SEGS + seg], a3.y);
    lds_fadd(&lsT[14*SEGS + seg], a3.z); lds_fadd(&lsT[15*SEGS + seg], a3.w);
    lds_fadd(&lsT[16*SEGS + seg], cnt);
}

__global__ void __launch_bounds__(NTHR, 3)
k_segsum(const float4* __restrict__ o4,
         const int* __restrict__ labels,
         const int* __restrict__ sub,
         float* __restrict__ seg_sum,
         float* __restrict__ seg_cnt,
         int n) {
    __shared__ float lsT[(DD + 1) * SEGS];  // planes [d][seg]; plane 16 = count
    for (int i = threadIdx.x; i < (DD + 1) * SEGS; i += NTHR) lsT[i] = 0.0f;
    __syncthreads();

    const int pbase = blockIdx.x * CHUNK + threadIdx.x;

    float4 c0 = {0,0,0,0}, c1 = {0,0,0,0}, c2 = {0,0,0,0}, c3 = {0,0,0,0};
    float cnt = 0.0f;
    int cur = -1;

    const bool full = ((long)(blockIdx.x + 1) * CHUNK) <= (long)n;
    if (full) {
        int lb[PPT], sb[PPT];
        float4 v0[PPT], v1[PPT], v2[PPT], v3[PPT];
        #pragma unroll
        for (int u = 0; u < PPT; ++u) {        // ints first: seg logic can
            int p = pbase + u * NTHR;          // start while float4s in flight
            lb[u] = labels[p];
            sb[u] = sub[p];
        }
        #pragma unroll
        for (int u = 0; u < PPT; ++u) {
            int p = pbase + u * NTHR;
            v0[u] = o4[4 * p + 0];
            v1[u] = o4[4 * p + 1];
            v2[u] = o4[4 * p + 2];
            v3[u] = o4[4 * p + 3];
        }
        __builtin_amdgcn_sched_barrier(0);     // loads may NOT sink past here
        #pragma unroll
        for (int u = 0; u < PPT; ++u) {
            int seg = sb[u] * MM + lb[u];
            float ss = v0[u].x*v0[u].x + v0[u].y*v0[u].y + v0[u].z*v0[u].z + v0[u].w*v0[u].w
                     + v1[u].x*v1[u].x + v1[u].y*v1[u].y + v1[u].z*v1[u].z + v1[u].w*v1[u].w
                     + v2[u].x*v2[u].x + v2[u].y*v2[u].y + v2[u].z*v2[u].z + v2[u].w*v2[u].w
                     + v3[u].x*v3[u].x + v3[u].y*v3[u].y + v3[u].z*v3[u].z + v3[u].w*v3[u].w;
            float rn = 1.0f / (sqrtf(ss) + NEPS);
            if (seg != cur) {                  // never fires for canonical input
                if (cur >= 0) flush_point(lsT, cur, c0, c1, c2, c3, cnt);
                c0 = c1 = c2 = c3 = (float4){0,0,0,0};
                cnt = 0.0f;
                cur = seg;
            }
            c0.x = fmaf(v0[u].x, rn, c0.x); c0.y = fmaf(v0[u].y, rn, c0.y);
            c0.z = fmaf(v0[u].z, rn, c0.z); c0.w = fmaf(v0[u].w, rn, c0.w);
            c1.x = fmaf(v1[u].x, rn, c1.x); c1.y = fmaf(v1[u].y, rn, c1.y);
            c1.z = fmaf(v1[u].z, rn, c1.z); c1.w = fmaf(v1[u].w, rn, c1.w);
            c2.x = fmaf(v2[u].x, rn, c2.x); c2.y = fmaf(v2[u].y, rn, c2.y);
            c2.z = fmaf(v2[u].z, rn, c2.z); c2.w = fmaf(v2[u].w, rn, c2.w);
            c3.x = fmaf(v3[u].x, rn, c3.x); c3.y = fmaf(v3[u].y, rn, c3.y);
            c3.z = fmaf(v3[u].z, rn, c3.z); c3.w = fmaf(v3[u].w, rn, c3.w);
            cnt += 1.0f;
        }
    } else {
        for (int u = 0; u < PPT; ++u) {        // guarded tail (non-canonical n)
            int p = pbase + u * NTHR;
            if (p >= n) break;
            float4 a = o4[4*p+0], b = o4[4*p+1], c = o4[4*p+2], e = o4[4*p+3];
            int seg = sub[p] * MM + labels[p];
            float ss = a.x*a.x + a.y*a.y + a.z*a.z + a.w*a.w
                     + b.x*b.x + b.y*b.y + b.z*b.z + b.w*b.w
                     + c.x*c.x + c.y*c.y + c.z*c.z + c.w*c.w
                     + e.x*e.x + e.y*e.y + e.z*e.z + e.w*e.w;
            float rn = 1.0f / (sqrtf(ss) + NEPS);
            if (seg != cur) {
                if (cur >= 0) flush_point(lsT, cur, c0, c1, c2, c3, cnt);
                c0 = c1 = c2 = c3 = (float4){0,0,0,0};
                cnt = 0.0f;
                cur = seg;
            }
            c0.x = fmaf(a.x, rn, c0.x); c0.y = fmaf(a.y, rn, c0.y);
            c0.z = fmaf(a.z, rn, c0.z); c0.w = fmaf(a.w, rn, c0.w);
            c1.x = fmaf(b.x, rn, c1.x); c1.y = fmaf(b.y, rn, c1.y);
            c1.z = fmaf(b.z, rn, c1.z); c1.w = fmaf(b.w, rn, c1.w);
            c2.x = fmaf(c.x, rn, c2.x); c2.y = fmaf(c.y, rn, c2.y);
            c2.z = fmaf(c.z, rn, c2.z); c2.w = fmaf(c.w, rn, c2.w);
            c3.x = fmaf(e.x, rn, c3.x); c3.y = fmaf(e.y, rn, c3.y);
            c3.z = fmaf(e.z, rn, c3.z); c3.w = fmaf(e.w, rn, c3.w);
            cnt += 1.0f;
        }
    }
    if (cur >= 0) flush_point(lsT, cur, c0, c1, c2, c3, cnt);
    __syncthreads();

    // global flush: only segments this block actually touched (count != 0)
    for (int s = threadIdx.x; s < SEGS; s += NTHR) {
        float c = lsT[DD * SEGS + s];
        if (c != 0.0f) {
            #pragma unroll
            for (int d = 0; d < DD; ++d)
                unsafeAtomicAdd(&seg_sum[s * DD + d], lsT[d * SEGS + s]);
            unsafeAtomicAdd(&seg_cnt[s], c);
        }
    }
}

__global__ void k_finalize_push(float* __restrict__ ws) {
    const float* seg_sum = ws;
    const float* seg_cnt = ws + 4096;
    float* mus  = ws + 4352;
    float* invw = ws + 8448;
    float* push = ws + 8704;

    __shared__ float muT[DD * SEGS];
    int t = threadIdx.x;  // 256 threads == one per segment
    float cnt = seg_cnt[t];
    float ic  = (cnt > 0.0f) ? 1.0f / cnt : 0.0f;
    #pragma unroll
    for (int d = 0; d < DD; ++d) {
        float m = seg_sum[t * DD + d] * ic;
        mus[t * DD + d]   = m;
        muT[d * SEGS + t] = m;
    }
    invw[t] = (cnt > 0.0f) ? 1.0f / ((float)MM * cnt) : 0.0f;
    __syncthreads();

    int b = t >> 5, m1 = t & 31;
    float acc = 0.0f;
    for (int m2 = 0; m2 < MM; ++m2) {
        float pd = 0.0f;
        #pragma unroll
        for (int d = 0; d < DD; ++d)
            pd += fabsf(muT[d * SEGS + b * MM + m1] - muT[d * SEGS + b * MM + m2]);
        float h = 2.0f * DELTA_D - pd;
        if (m2 != m1 && h > 0.0f) acc += h * h;
    }
    float tot = block_reduce_sum(acc);
    if (t == 0) push[0] = tot / (float)(MM * (MM - 1));
}

__global__ void __launch_bounds__(NTHR, 3)
k_pull(const float4* __restrict__ o4,
       const int* __restrict__ labels,
       const int* __restrict__ sub,
       const float* __restrict__ mus,
       const float* __restrict__ invw,
       float* __restrict__ pull_part,
       int n) {
    __shared__ float muL[DD * SEGS];  // seg-major (matches ws mus layout)
    __shared__ float siw[SEGS];
    for (int i = threadIdx.x; i < DD * SEGS; i += NTHR) muL[i] = mus[i];
    for (int i = threadIdx.x; i < SEGS; i += NTHR) siw[i] = invw[i];
    __syncthreads();

    const int pbase = blockIdx.x * CHUNK + threadIdx.x;

    float4 m0, m1, m2, m3;
    float iw = 0.0f;
    int cur = -1;
    float acc = 0.0f;

    const bool full = ((long)(blockIdx.x + 1) * CHUNK) <= (long)n;
    if (full) {
        int lb[PPT], sb[PPT];
        float4 v0[PPT], v1[PPT], v2[PPT], v3[PPT];
        #pragma unroll
        for (int u = 0; u < PPT; ++u) {
            int p = pbase + u * NTHR;
            lb[u] = labels[p];
            sb[u] = sub[p];
        }
        #pragma unroll
        for (int u = 0; u < PPT; ++u) {
            int p = pbase + u * NTHR;
            v0[u] = o4[4 * p + 0];
            v1[u] = o4[4 * p + 1];
            v2[u] = o4[4 * p + 2];
            v3[u] = o4[4 * p + 3];
        }
        __builtin_amdgcn_sched_barrier(0);
        #pragma unroll
        for (int u = 0; u < PPT; ++u) {
            int seg = sb[u] * MM + lb[u];
            if (seg != cur) {                  // once per thread for canonical input
                cur = seg;
                m0 = *(const float4*)&muL[seg * DD +  0];
                m1 = *(const float4*)&muL[seg * DD +  4];
                m2 = *(const float4*)&muL[seg * DD +  8];
                m3 = *(const float4*)&muL[seg * DD + 12];
                iw = siw[seg];
            }
            float ss = v0[u].x*v0[u].x + v0[u].y*v0[u].y + v0[u].z*v0[u].z + v0[u].w*v0[u].w
                     + v1[u].x*v1[u].x + v1[u].y*v1[u].y + v1[u].z*v1[u].z + v1[u].w*v1[u].w
                     + v2[u].x*v2[u].x + v2[u].y*v2[u].y + v2[u].z*v2[u].z + v2[u].w*v2[u].w
                     + v3[u].x*v3[u].x + v3[u].y*v3[u].y + v3[u].z*v3[u].z + v3[u].w*v3[u].w;
            float rn = 1.0f / (sqrtf(ss) + NEPS);
            float dist;
            dist  = fabsf(m0.x - v0[u].x * rn) + fabsf(m0.y - v0[u].y * rn)
                  + fabsf(m0.z - v0[u].z * rn) + fabsf(m0.w - v0[u].w * rn);
            dist += fabsf(m1.x - v1[u].x * rn) + fabsf(m1.y - v1[u].y * rn)
                  + fabsf(m1.z - v1[u].z * rn) + fabsf(m1.w - v1[u].w * rn);
            dist += fabsf(m2.x - v2[u].x * rn) + fabsf(m2.y - v2[u].y * rn)
                  + fabsf(m2.z - v2[u].z * rn) + fabsf(m2.w - v2[u].w * rn);
            dist += fabsf(m3.x - v3[u].x * rn) + fabsf(m3.y - v3[u].y * rn)
                  + fabsf(m3.z - v3[u].z * rn) + fabsf(m3.w - v3[u].w * rn);
            float h = dist - DELTA_V;
            if (h > 0.0f) acc = fmaf(h * h, iw, acc);
        }
    } else {
        for (int u = 0; u < PPT; ++u) {
            int p = pbase + u * NTHR;
            if (p >= n) break;
            float4 a = o4[4*p+0], b = o4[4*p+1], c = o4[4*p+2], e = o4[4*p+3];
            int seg = sub[p] * MM + labels[p];
            if (seg != cur) {
                cur = seg;
                m0 = *(const float4*)&muL[seg * DD +  0];
                m1 = *(const float4*)&muL[seg * DD +  4];
                m2 = *(const float4*)&muL[seg * DD +  8];
                m3 = *(const float4*)&muL[seg * DD + 12];
                iw = siw[seg];
            }
            float ss = a.x*a.x + a.y*a.y + a.z*a.z + a.w*a.w
                     + b.x*b.x + b.y*b.y + b.z*b.z + b.w*b.w
                     + c.x*c.x + c.y*c.y + c.z*c.z + c.w*c.w
                     + e.x*e.x + e.y*e.y + e.z*e.z + e.w*e.w;
            float rn = 1.0f / (sqrtf(ss) + NEPS);
            float dist;
            dist  = fabsf(m0.x - a.x * rn) + fabsf(m0.y - a.y * rn)
                  + fabsf(m0.z - a.z * rn) + fabsf(m0.w - a.w * rn);
            dist += fabsf(m1.x - b.x * rn) + fabsf(m1.y - b.y * rn)
                  + fabsf(m1.z - b.z * rn) + fabsf(m1.w - b.w * rn);
            dist += fabsf(m2.x - c.x * rn) + fabsf(m2.y - c.y * rn)
                  + fabsf(m2.z - c.z * rn) + fabsf(m2.w - c.w * rn);
            dist += fabsf(m3.x - e.x * rn) + fabsf(m3.y - e.y * rn)
                  + fabsf(m3.z - e.z * rn) + fabsf(m3.w - e.w * rn);
            float h = dist - DELTA_V;
            if (h > 0.0f) acc = fmaf(h * h, iw, acc);
        }
    }
    float tot = block_reduce_sum(acc);
    if (threadIdx.x == 0) pull_part[blockIdx.x] = tot;
}

__global__ void k_final(const float* __restrict__ ws, float* __restrict__ out,
                        int nblk) {
    const float* push      = ws + 8704;
    const float* pull_part = ws + 8720;
    int t = threadIdx.x;
    float v = 0.0f;
    for (int k = t; k < nblk; k += NTHR) v += pull_part[k];
    float tot = block_reduce_sum(v);
    if (t == 0) out[0] = (tot + push[0]) * (1.0f / (float)BBATCH);
}

extern "C" void kernel_launch(void* const* d_in, const int* in_sizes, int n_in,
                              void* d_out, int out_size, void* d_ws, size_t ws_size,
                              hipStream_t stream) {
    const float* outputs = (const float*)d_in[0];
    const int* labels    = (const int*)d_in[1];
    const int* sub       = (const int*)d_in[2];
    int n = in_sizes[0] / DD;

    float* ws        = (float*)d_ws;
    float* seg_sum   = ws;
    float* seg_cnt   = ws + 4096;
    float* mus       = ws + 4352;
    float* invw      = ws + 8448;
    float* pull_part = ws + 8720;

    int nblk = (n + CHUNK - 1) / CHUNK;        // 2048 for canonical N
    if (nblk > MAXBLK) nblk = MAXBLK;          // (cannot happen for this problem)

    hipMemsetAsync(d_ws, 0, WS_ZERO_FLOATS * sizeof(float), stream);

    k_segsum<<<nblk, NTHR, 0, stream>>>((const float4*)outputs, labels, sub,
                                        seg_sum, seg_cnt, n);
    k_finalize_push<<<1, NTHR, 0, stream>>>(ws);
    k_pull<<<nblk, NTHR, 0, stream>>>((const float4*)outputs, labels, sub,
                                      mus, invw, pull_part, n);
    k_final<<<1, NTHR, 0, stream>>>(ws, (float*)d_out, nblk);
}

// Round 3
// 391.451 us; speedup vs baseline: 1.0608x; 1.0049x over previous
//
#include <hip/hip_runtime.h>
#include <math.h>

// CentroidInstanceLoss: N=2M points, D=16, B=8 subbatches, M=32 labels.
// out = (L_pull + L_push)/B  (single fp32 scalar)
//
// R7: atomic-contention fix. Evidence: segsum time tracks BLOCK COUNT not load
// structure (R4 1024blk=139us, R5/R6 2048blk=267/240us), WRITE_SIZE is exactly
// proportional to atomic count. Device-scope fp32 atomics resolve memory-side
// (per-XCD L2s non-coherent); all blocks of a sub-batch serialized on the SAME
// 34 seg_sum lines: (blocks/sub)*16 atomics/line * ~60ns == measured duration.
// Fix: KP=32 replicated partial accumulators (pp[bid&31][seg][17]) -> 16x less
// per-line serialization; finalize reduces the partials. Also PPT=2 (fewer
// serialized load round trips/thread, the only load-side lever with measured
// support) and launch_bounds(256,8) so 8 blocks/CU can be resident.

#define DD 16
#define MM 32
#define BBATCH 8
#define SEGS 256          // B*M
#define DELTA_V 0.5f
#define DELTA_D 1.5f
#define NEPS 1e-8f

#define NTHR 256
#define PPT 2                 // points per thread per chunk
#define CHUNK (NTHR * PPT)    // 512 points per block-chunk; canonical nblk=4096
#define KP 32                 // replicated partial accumulators
#define MAXBLK 8192

// ws layout (floats):
//   [OFF_PP,   +KP*4352)  partials  [k][seg][17]  (d=16 is count)
//   [OFF_MUS,  +4096)     mus       [seg][16]  (seg-major)
//   [OFF_INVW, +256)      invw      [seg] = 1/(M*count)
//   [OFF_PUSH, +16)       push_acc
//   [OFF_PULL, +MAXBLK)   pull_part
#define OFF_PP    0
#define OFF_MUS   (KP * 4352)
#define OFF_INVW  (OFF_MUS + 4096)
#define OFF_PUSH  (OFF_INVW + 256)
#define OFF_PULL  (OFF_PUSH + 16)
#define WS_ZERO_FLOATS (KP * 4352)

__device__ __forceinline__ void lds_fadd(float* p, float v) {
    __hip_atomic_fetch_add(p, v, __ATOMIC_RELAXED, __HIP_MEMORY_SCOPE_WORKGROUP);
}

__device__ __forceinline__ float block_reduce_sum(float v) {
    #pragma unroll
    for (int o = 32; o > 0; o >>= 1) v += __shfl_down(v, o, 64);
    __shared__ float red[4];
    int wid  = threadIdx.x >> 6;
    int lane = threadIdx.x & 63;
    if (lane == 0) red[wid] = v;
    __syncthreads();
    v = (threadIdx.x < (NTHR >> 6)) ? red[threadIdx.x] : 0.0f;
    if (wid == 0) {
        #pragma unroll
        for (int o = 32; o > 0; o >>= 1) v += __shfl_down(v, o, 64);
    }
    return v;  // valid on thread 0
}

// flush a full-point accumulator (16 floats + count) into transposed LDS planes
__device__ __forceinline__ void flush_point(float* lsT, int seg,
                                            float4 a0, float4 a1,
                                            float4 a2, float4 a3, float cnt) {
    lds_fadd(&lsT[ 0*SEGS + seg], a0.x); lds_fadd(&lsT[ 1*SEGS + seg], a0.y);
    lds_fadd(&lsT[ 2*SEGS + seg], a0.z); lds_fadd(&lsT[ 3*SEGS + seg], a0.w);
    lds_fadd(&lsT[ 4*SEGS + seg], a1.x); lds_fadd(&lsT[ 5*SEGS + seg], a1.y);
    lds_fadd(&lsT[ 6*SEGS + seg], a1.z); lds_fadd(&lsT[ 7*SEGS + seg], a1.w);
    lds_fadd(&lsT[ 8*SEGS + seg], a2.x); lds_fadd(&lsT[ 9*SEGS + seg], a2.y);
    lds_fadd(&lsT[10*SEGS + seg], a2.z); lds_fadd(&lsT[11*SEGS + seg], a2.w);
    lds_fadd(&lsT[12*SEGS + seg], a3.x); lds_fadd(&lsT[13*SEGS + seg], a3.y);
    lds_fadd(&lsT[14*SEGS + seg], a3.z); lds_fadd(&lsT[15*SEGS + seg], a3.w);
    lds_fadd(&lsT[16*SEGS + seg], cnt);
}

__global__ void __launch_bounds__(NTHR, 8)
k_segsum(const float4* __restrict__ o4,
         const int* __restrict__ labels,
         const int* __restrict__ sub,
         float* __restrict__ pp,
         int n) {
    __shared__ float lsT[(DD + 1) * SEGS];  // planes [d][seg]; plane 16 = count
    for (int i = threadIdx.x; i < (DD + 1) * SEGS; i += NTHR) lsT[i] = 0.0f;
    __syncthreads();

    float4 c0 = {0,0,0,0}, c1 = {0,0,0,0}, c2 = {0,0,0,0}, c3 = {0,0,0,0};
    float cnt = 0.0f;
    int cur = -1;

    for (long cb = blockIdx.x; cb * CHUNK < (long)n; cb += gridDim.x) {
        const int pbase = (int)(cb * CHUNK) + threadIdx.x;
        #pragma unroll
        for (int u = 0; u < PPT; ++u) {
            int p = pbase + u * NTHR;
            if (p >= n) break;
            int lb = labels[p];
            int sv = sub[p];
            float4 a = o4[4*p+0], b = o4[4*p+1], c = o4[4*p+2], e = o4[4*p+3];
            int seg = sv * MM + lb;
            float ss = a.x*a.x + a.y*a.y + a.z*a.z + a.w*a.w
                     + b.x*b.x + b.y*b.y + b.z*b.z + b.w*b.w
                     + c.x*c.x + c.y*c.y + c.z*c.z + c.w*c.w
                     + e.x*e.x + e.y*e.y + e.z*e.z + e.w*e.w;
            float rn = 1.0f / (sqrtf(ss) + NEPS);
            if (seg != cur) {                  // never fires for canonical input
                if (cur >= 0) flush_point(lsT, cur, c0, c1, c2, c3, cnt);
                c0 = c1 = c2 = c3 = (float4){0,0,0,0};
                cnt = 0.0f;
                cur = seg;
            }
            c0.x = fmaf(a.x, rn, c0.x); c0.y = fmaf(a.y, rn, c0.y);
            c0.z = fmaf(a.z, rn, c0.z); c0.w = fmaf(a.w, rn, c0.w);
            c1.x = fmaf(b.x, rn, c1.x); c1.y = fmaf(b.y, rn, c1.y);
            c1.z = fmaf(b.z, rn, c1.z); c1.w = fmaf(b.w, rn, c1.w);
            c2.x = fmaf(c.x, rn, c2.x); c2.y = fmaf(c.y, rn, c2.y);
            c2.z = fmaf(c.z, rn, c2.z); c2.w = fmaf(c.w, rn, c2.w);
            c3.x = fmaf(e.x, rn, c3.x); c3.y = fmaf(e.y, rn, c3.y);
            c3.z = fmaf(e.z, rn, c3.z); c3.w = fmaf(e.w, rn, c3.w);
            cnt += 1.0f;
        }
    }
    if (cur >= 0) flush_point(lsT, cur, c0, c1, c2, c3, cnt);
    __syncthreads();

    // flush to this block's replicated partial copy: 16x less same-line
    // contention than a single shared seg_sum.
    float* dst = pp + (size_t)(blockIdx.x & (KP - 1)) * (SEGS * 17);
    for (int s = threadIdx.x; s < SEGS; s += NTHR) {
        float c = lsT[DD * SEGS + s];
        if (c != 0.0f) {
            #pragma unroll
            for (int d = 0; d < DD; ++d)
                unsafeAtomicAdd(&dst[s * 17 + d], lsT[d * SEGS + s]);
            unsafeAtomicAdd(&dst[s * 17 + 16], c);
        }
    }
}

__global__ void k_finalize_push(float* __restrict__ ws) {
    const float* pp = ws + OFF_PP;
    float* mus  = ws + OFF_MUS;
    float* invw = ws + OFF_INVW;
    float* push = ws + OFF_PUSH;

    __shared__ float muT[DD * SEGS];
    int t = threadIdx.x;  // 256 threads == one per segment

    // reduce the KP partial copies
    float s17[DD + 1];
    #pragma unroll
    for (int d = 0; d <= DD; ++d) s17[d] = 0.0f;
    for (int k = 0; k < KP; ++k) {
        const float* src = pp + (size_t)k * (SEGS * 17) + t * 17;
        #pragma unroll
        for (int d = 0; d <= DD; ++d) s17[d] += src[d];
    }
    float cnt = s17[DD];
    float ic  = (cnt > 0.0f) ? 1.0f / cnt : 0.0f;
    #pragma unroll
    for (int d = 0; d < DD; ++d) {
        float m = s17[d] * ic;
        mus[t * DD + d]   = m;
        muT[d * SEGS + t] = m;
    }
    invw[t] = (cnt > 0.0f) ? 1.0f / ((float)MM * cnt) : 0.0f;
    __syncthreads();

    int b = t >> 5, m1 = t & 31;
    float acc = 0.0f;
    for (int m2 = 0; m2 < MM; ++m2) {
        float pd = 0.0f;
        #pragma unroll
        for (int d = 0; d < DD; ++d)
            pd += fabsf(muT[d * SEGS + b * MM + m1] - muT[d * SEGS + b * MM + m2]);
        float h = 2.0f * DELTA_D - pd;
        if (m2 != m1 && h > 0.0f) acc += h * h;
    }
    float tot = block_reduce_sum(acc);
    if (t == 0) push[0] = tot / (float)(MM * (MM - 1));
}

__global__ void __launch_bounds__(NTHR, 8)
k_pull(const float4* __restrict__ o4,
       const int* __restrict__ labels,
       const int* __restrict__ sub,
       const float* __restrict__ mus,
       const float* __restrict__ invw,
       float* __restrict__ pull_part,
       int n) {
    __shared__ float muL[DD * SEGS];  // seg-major (matches ws mus layout)
    __shared__ float siw[SEGS];
    for (int i = threadIdx.x; i < DD * SEGS; i += NTHR) muL[i] = mus[i];
    for (int i = threadIdx.x; i < SEGS; i += NTHR) siw[i] = invw[i];
    __syncthreads();

    float4 m0, m1, m2, m3;
    float iw = 0.0f;
    int cur = -1;
    float acc = 0.0f;

    for (long cb = blockIdx.x; cb * CHUNK < (long)n; cb += gridDim.x) {
        const int pbase = (int)(cb * CHUNK) + threadIdx.x;
        #pragma unroll
        for (int u = 0; u < PPT; ++u) {
            int p = pbase + u * NTHR;
            if (p >= n) break;
            int lb = labels[p];
            int sv = sub[p];
            float4 a = o4[4*p+0], b = o4[4*p+1], c = o4[4*p+2], e = o4[4*p+3];
            int seg = sv * MM + lb;
            if (seg != cur) {                  // once per thread for canonical input
                cur = seg;
                m0 = *(const float4*)&muL[seg * DD +  0];
                m1 = *(const float4*)&muL[seg * DD +  4];
                m2 = *(const float4*)&muL[seg * DD +  8];
                m3 = *(const float4*)&muL[seg * DD + 12];
                iw = siw[seg];
            }
            float ss = a.x*a.x + a.y*a.y + a.z*a.z + a.w*a.w
                     + b.x*b.x + b.y*b.y + b.z*b.z + b.w*b.w
                     + c.x*c.x + c.y*c.y + c.z*c.z + c.w*c.w
                     + e.x*e.x + e.y*e.y + e.z*e.z + e.w*e.w;
            float rn = 1.0f / (sqrtf(ss) + NEPS);
            float dist;
            dist  = fabsf(m0.x - a.x * rn) + fabsf(m0.y - a.y * rn)
                  + fabsf(m0.z - a.z * rn) + fabsf(m0.w - a.w * rn);
            dist += fabsf(m1.x - b.x * rn) + fabsf(m1.y - b.y * rn)
                  + fabsf(m1.z - b.z * rn) + fabsf(m1.w - b.w * rn);
            dist += fabsf(m2.x - c.x * rn) + fabsf(m2.y - c.y * rn)
                  + fabsf(m2.z - c.z * rn) + fabsf(m2.w - c.w * rn);
            dist += fabsf(m3.x - e.x * rn) + fabsf(m3.y - e.y * rn)
                  + fabsf(m3.z - e.z * rn) + fabsf(m3.w - e.w * rn);
            float h = dist - DELTA_V;
            if (h > 0.0f) acc = fmaf(h * h, iw, acc);
        }
    }
    float tot = block_reduce_sum(acc);
    if (threadIdx.x == 0) pull_part[blockIdx.x] = tot;
}

__global__ void k_final(const float* __restrict__ ws, float* __restrict__ out,
                        int nblk) {
    const float* push      = ws + OFF_PUSH;
    const float* pull_part = ws + OFF_PULL;
    int t = threadIdx.x;
    float v = 0.0f;
    for (int k = t; k < nblk; k += NTHR) v += pull_part[k];
    float tot = block_reduce_sum(v);
    if (t == 0) out[0] = (tot + push[0]) * (1.0f / (float)BBATCH);
}

extern "C" void kernel_launch(void* const* d_in, const int* in_sizes, int n_in,
                              void* d_out, int out_size, void* d_ws, size_t ws_size,
                              hipStream_t stream) {
    const float* outputs = (const float*)d_in[0];
    const int* labels    = (const int*)d_in[1];
    const int* sub       = (const int*)d_in[2];
    int n = in_sizes[0] / DD;

    float* ws        = (float*)d_ws;
    float* pp        = ws + OFF_PP;
    float* mus       = ws + OFF_MUS;
    float* invw      = ws + OFF_INVW;
    float* pull_part = ws + OFF_PULL;

    long nblk_l = ((long)n + CHUNK - 1) / CHUNK;   // 4096 for canonical N
    int nblk = (nblk_l > MAXBLK) ? MAXBLK : (int)nblk_l;

    hipMemsetAsync(d_ws, 0, (size_t)WS_ZERO_FLOATS * sizeof(float), stream);

    k_segsum<<<nblk, NTHR, 0, stream>>>((const float4*)outputs, labels, sub,
                                        pp, n);
    k_finalize_push<<<1, NTHR, 0, stream>>>(ws);
    k_pull<<<nblk, NTHR, 0, stream>>>((const float4*)outputs, labels, sub,
                                      mus, invw, pull_part, n);
    k_final<<<1, NTHR, 0, stream>>>(ws, (float*)d_out, nblk);
}

// Round 4
// 299.424 us; speedup vs baseline: 1.3869x; 1.3073x over previous
//
#include <hip/hip_runtime.h>
#include <math.h>

// CentroidInstanceLoss: N=2M points, D=16, B=8 subbatches, M=32 labels.
// out = (L_pull + L_push)/B  (single fp32 scalar)
//
// R8: async global->LDS staging. R4-R7 evidence: both streaming kernels stuck
// at ~0.7-1.0 TB/s with VALUBusy 3%, HBM 8%, 0 bank conflicts -- latency-bound
// with only ~1-2 load-instrs in flight per wave (VGPR=28-48 across 3 failed
// register-batching attempts: the allocator always re-serializes). Fix: the
// prefetch buffer is LDS, not VGPRs. Each wave issues 6 global_load_lds per
// 256-point tile (4x 1KB data + labels + sub), double-buffered 2 tiles deep,
// waited with counted s_waitcnt vmcnt(6) (never 0 in steady state). Staging is
// wave-local (each wave stages exactly the points its own lanes consume) -> no
// __syncthreads in the pipeline at all. Global side is lane-contiguous 1KB per
// instr; a 16B-slot involution (pos ^ ((pos>>3)&3)) pre-swizzles the GLOBAL
// source (gload_lds writes linearly, rule: swizzle both-sides-or-neither) so
// the per-point float4 LDS reads cover all 8 bank-quads (bandwidth floor).

#define DD 16
#define MM 32
#define BBATCH 8
#define SEGS 256          // B*M
#define DELTA_V 0.5f
#define DELTA_D 1.5f
#define NEPS 1e-8f

#define NTHR 256
#define TILE_PTS 256                    // one point per thread per tile
#define TPB 8                           // tiles per chunk
#define CHUNK_PTS (TILE_PTS * TPB)      // 2048 points; canonical nchunks=1024
#define DEPTH 2                         // LDS double-buffer
#define KP 32                           // replicated global partials (R7 win)
#define MAXBLK 2048

// ws layout (floats):
//   [OFF_PP,   +KP*4352)  partials  [k][seg][17]  (d=16 is count)
//   [OFF_MUS,  +4096)     mus       [seg][16]  (seg-major)
//   [OFF_INVW, +256)      invw      [seg] = 1/(M*count)
//   [OFF_PUSH, +16)       push_acc
//   [OFF_PULL, +MAXBLK)   pull_part
#define OFF_PP    0
#define OFF_MUS   (KP * 4352)
#define OFF_INVW  (OFF_MUS + 4096)
#define OFF_PUSH  (OFF_INVW + 256)
#define OFF_PULL  (OFF_PUSH + 16)
#define WS_ZERO_FLOATS (KP * 4352)

__device__ __forceinline__ void gload16(const void* g, void* l) {
    __builtin_amdgcn_global_load_lds(
        (const __attribute__((address_space(1))) void*)g,
        (__attribute__((address_space(3))) void*)l, 16, 0, 0);
}
__device__ __forceinline__ void gload4(const void* g, void* l) {
    __builtin_amdgcn_global_load_lds(
        (const __attribute__((address_space(1))) void*)g,
        (__attribute__((address_space(3))) void*)l, 4, 0, 0);
}

__device__ __forceinline__ void lds_fadd(float* p, float v) {
    __hip_atomic_fetch_add(p, v, __ATOMIC_RELAXED, __HIP_MEMORY_SCOPE_WORKGROUP);
}

__device__ __forceinline__ float block_reduce_sum(float v) {
    #pragma unroll
    for (int o = 32; o > 0; o >>= 1) v += __shfl_down(v, o, 64);
    __shared__ float red[4];
    int wid  = threadIdx.x >> 6;
    int lane = threadIdx.x & 63;
    if (lane == 0) red[wid] = v;
    __syncthreads();
    v = (threadIdx.x < (NTHR >> 6)) ? red[threadIdx.x] : 0.0f;
    if (wid == 0) {
        #pragma unroll
        for (int o = 32; o > 0; o >>= 1) v += __shfl_down(v, o, 64);
    }
    return v;  // valid on thread 0
}

// flush a full-point accumulator (16 floats + count) into transposed LDS planes
__device__ __forceinline__ void flush_point(float* lsT, int seg,
                                            float4 a0, float4 a1,
                                            float4 a2, float4 a3, float cnt) {
    lds_fadd(&lsT[ 0*SEGS + seg], a0.x); lds_fadd(&lsT[ 1*SEGS + seg], a0.y);
    lds_fadd(&lsT[ 2*SEGS + seg], a0.z); lds_fadd(&lsT[ 3*SEGS + seg], a0.w);
    lds_fadd(&lsT[ 4*SEGS + seg], a1.x); lds_fadd(&lsT[ 5*SEGS + seg], a1.y);
    lds_fadd(&lsT[ 6*SEGS + seg], a1.z); lds_fadd(&lsT[ 7*SEGS + seg], a1.w);
    lds_fadd(&lsT[ 8*SEGS + seg], a2.x); lds_fadd(&lsT[ 9*SEGS + seg], a2.y);
    lds_fadd(&lsT[10*SEGS + seg], a2.z); lds_fadd(&lsT[11*SEGS + seg], a2.w);
    lds_fadd(&lsT[12*SEGS + seg], a3.x); lds_fadd(&lsT[13*SEGS + seg], a3.y);
    lds_fadd(&lsT[14*SEGS + seg], a3.z); lds_fadd(&lsT[15*SEGS + seg], a3.w);
    lds_fadd(&lsT[16*SEGS + seg], cnt);
}

// Stage one 256-point tile (wave-local): 4x 1KB data + labels + sub.
// LDS dest is linear (HW: wave-uniform base + lane*size); the GLOBAL slot
// index carries the involution q ^ ((q>>3)&3) so reads can de-swizzle.
#define STAGE_TILE(bi_, pb_) do {                                              \
    const float* gs_ = (const float*)o4 + (size_t)(pb_) * DD;                  \
    { int q_ = (w << 8) +   0 + lane;                                          \
      gload16(gs_ + (q_ ^ ((q_ >> 3) & 3)) * 4, &dbuf[bi_][((w << 8) +   0) * 4]); } \
    { int q_ = (w << 8) +  64 + lane;                                          \
      gload16(gs_ + (q_ ^ ((q_ >> 3) & 3)) * 4, &dbuf[bi_][((w << 8) +  64) * 4]); } \
    { int q_ = (w << 8) + 128 + lane;                                          \
      gload16(gs_ + (q_ ^ ((q_ >> 3) & 3)) * 4, &dbuf[bi_][((w << 8) + 128) * 4]); } \
    { int q_ = (w << 8) + 192 + lane;                                          \
      gload16(gs_ + (q_ ^ ((q_ >> 3) & 3)) * 4, &dbuf[bi_][((w << 8) + 192) * 4]); } \
    gload4(labels + (pb_) + (w << 6) + lane, &labbuf[bi_][w << 6]);            \
    gload4(sub    + (pb_) + (w << 6) + lane, &subbuf[bi_][w << 6]);            \
} while (0)

__global__ void __launch_bounds__(NTHR)
k_segsum(const float4* __restrict__ o4,
         const int* __restrict__ labels,
         const int* __restrict__ sub,
         float* __restrict__ pp,
         int n) {
    __shared__ float lsT[(DD + 1) * SEGS];        // 17 KB
    __shared__ float dbuf[DEPTH][TILE_PTS * DD];  // 32 KB
    __shared__ int   labbuf[DEPTH][TILE_PTS];     // 2 KB
    __shared__ int   subbuf[DEPTH][TILE_PTS];
    for (int i = threadIdx.x; i < (DD + 1) * SEGS; i += NTHR) lsT[i] = 0.0f;
    __syncthreads();

    const int t    = threadIdx.x;
    const int w    = t >> 6;
    const int lane = t & 63;
    const int xm   = (t >> 1) & 3;   // read-side involution bits for this point

    float4 c0 = {0,0,0,0}, c1 = {0,0,0,0}, c2 = {0,0,0,0}, c3 = {0,0,0,0};
    float cnt = 0.0f;
    int cur = -1;

    const int nchunks = n / CHUNK_PTS;
    for (int cb = blockIdx.x; cb < nchunks; cb += gridDim.x) {
        const int pbase = cb * CHUNK_PTS;
        STAGE_TILE(0, pbase + 0 * TILE_PTS);
        STAGE_TILE(1, pbase + 1 * TILE_PTS);
        #pragma unroll
        for (int ti = 0; ti < TPB; ++ti) {
            const int bi = ti & 1;
            if (ti < TPB - 1) asm volatile("s_waitcnt vmcnt(6)" ::: "memory");
            else              asm volatile("s_waitcnt vmcnt(0)" ::: "memory");
            int lb = labbuf[bi][t];
            int sv = subbuf[bi][t];
            const float* db = &dbuf[bi][0];
            float4 a = *(const float4*)&db[((4*t + 0) ^ xm) * 4];
            float4 b = *(const float4*)&db[((4*t + 1) ^ xm) * 4];
            float4 c = *(const float4*)&db[((4*t + 2) ^ xm) * 4];
            float4 e = *(const float4*)&db[((4*t + 3) ^ xm) * 4];
            int seg = sv * MM + lb;
            float ss = a.x*a.x + a.y*a.y + a.z*a.z + a.w*a.w
                     + b.x*b.x + b.y*b.y + b.z*b.z + b.w*b.w
                     + c.x*c.x + c.y*c.y + c.z*c.z + c.w*c.w
                     + e.x*e.x + e.y*e.y + e.z*e.z + e.w*e.w;
            float rn = 1.0f / (sqrtf(ss) + NEPS);
            if (seg != cur) {                  // never fires for canonical input
                if (cur >= 0) flush_point(lsT, cur, c0, c1, c2, c3, cnt);
                c0 = c1 = c2 = c3 = (float4){0,0,0,0};
                cnt = 0.0f;
                cur = seg;
            }
            c0.x = fmaf(a.x, rn, c0.x); c0.y = fmaf(a.y, rn, c0.y);
            c0.z = fmaf(a.z, rn, c0.z); c0.w = fmaf(a.w, rn, c0.w);
            c1.x = fmaf(b.x, rn, c1.x); c1.y = fmaf(b.y, rn, c1.y);
            c1.z = fmaf(b.z, rn, c1.z); c1.w = fmaf(b.w, rn, c1.w);
            c2.x = fmaf(c.x, rn, c2.x); c2.y = fmaf(c.y, rn, c2.y);
            c2.z = fmaf(c.z, rn, c2.z); c2.w = fmaf(c.w, rn, c2.w);
            c3.x = fmaf(e.x, rn, c3.x); c3.y = fmaf(e.y, rn, c3.y);
            c3.z = fmaf(e.z, rn, c3.z); c3.w = fmaf(e.w, rn, c3.w);
            cnt += 1.0f;
            __builtin_amdgcn_sched_barrier(0);   // keep re-stage after consume
            if (ti + 2 < TPB) STAGE_TILE(bi, pbase + (ti + 2) * TILE_PTS);
        }
    }
    // tail points (non-canonical n only): simple direct-global path, block 0
    if (blockIdx.x == 0) {
        for (int p = nchunks * CHUNK_PTS + t; p < n; p += NTHR) {
            float4 a = o4[4*p+0], b = o4[4*p+1], c = o4[4*p+2], e = o4[4*p+3];
            int seg = sub[p] * MM + labels[p];
            float ss = a.x*a.x + a.y*a.y + a.z*a.z + a.w*a.w
                     + b.x*b.x + b.y*b.y + b.z*b.z + b.w*b.w
                     + c.x*c.x + c.y*c.y + c.z*c.z + c.w*c.w
                     + e.x*e.x + e.y*e.y + e.z*e.z + e.w*e.w;
            float rn = 1.0f / (sqrtf(ss) + NEPS);
            if (seg != cur) {
                if (cur >= 0) flush_point(lsT, cur, c0, c1, c2, c3, cnt);
                c0 = c1 = c2 = c3 = (float4){0,0,0,0};
                cnt = 0.0f;
                cur = seg;
            }
            c0.x = fmaf(a.x, rn, c0.x); c0.y = fmaf(a.y, rn, c0.y);
            c0.z = fmaf(a.z, rn, c0.z); c0.w = fmaf(a.w, rn, c0.w);
            c1.x = fmaf(b.x, rn, c1.x); c1.y = fmaf(b.y, rn, c1.y);
            c1.z = fmaf(b.z, rn, c1.z); c1.w = fmaf(b.w, rn, c1.w);
            c2.x = fmaf(c.x, rn, c2.x); c2.y = fmaf(c.y, rn, c2.y);
            c2.z = fmaf(c.z, rn, c2.z); c2.w = fmaf(c.w, rn, c2.w);
            c3.x = fmaf(e.x, rn, c3.x); c3.y = fmaf(e.y, rn, c3.y);
            c3.z = fmaf(e.z, rn, c3.z); c3.w = fmaf(e.w, rn, c3.w);
            cnt += 1.0f;
        }
    }
    if (cur >= 0) flush_point(lsT, cur, c0, c1, c2, c3, cnt);
    __syncthreads();

    // flush to this block's replicated partial copy (R7: kills same-line chains)
    float* dst = pp + (size_t)(blockIdx.x & (KP - 1)) * (SEGS * 17);
    for (int s = threadIdx.x; s < SEGS; s += NTHR) {
        float c = lsT[DD * SEGS + s];
        if (c != 0.0f) {
            #pragma unroll
            for (int d = 0; d < DD; ++d)
                unsafeAtomicAdd(&dst[s * 17 + d], lsT[d * SEGS + s]);
            unsafeAtomicAdd(&dst[s * 17 + 16], c);
        }
    }
}

__global__ void k_finalize_push(float* __restrict__ ws) {
    const float* pp = ws + OFF_PP;
    float* mus  = ws + OFF_MUS;
    float* invw = ws + OFF_INVW;
    float* push = ws + OFF_PUSH;

    __shared__ float muT[DD * SEGS];
    int t = threadIdx.x;  // 256 threads == one per segment

    float s17[DD + 1];
    #pragma unroll
    for (int d = 0; d <= DD; ++d) s17[d] = 0.0f;
    for (int k = 0; k < KP; ++k) {
        const float* src = pp + (size_t)k * (SEGS * 17) + t * 17;
        #pragma unroll
        for (int d = 0; d <= DD; ++d) s17[d] += src[d];
    }
    float cnt = s17[DD];
    float ic  = (cnt > 0.0f) ? 1.0f / cnt : 0.0f;
    #pragma unroll
    for (int d = 0; d < DD; ++d) {
        float m = s17[d] * ic;
        mus[t * DD + d]   = m;
        muT[d * SEGS + t] = m;
    }
    invw[t] = (cnt > 0.0f) ? 1.0f / ((float)MM * cnt) : 0.0f;
    __syncthreads();

    int b = t >> 5, m1 = t & 31;
    float acc = 0.0f;
    for (int m2 = 0; m2 < MM; ++m2) {
        float pd = 0.0f;
        #pragma unroll
        for (int d = 0; d < DD; ++d)
            pd += fabsf(muT[d * SEGS + b * MM + m1] - muT[d * SEGS + b * MM + m2]);
        float h = 2.0f * DELTA_D - pd;
        if (m2 != m1 && h > 0.0f) acc += h * h;
    }
    float tot = block_reduce_sum(acc);
    if (t == 0) push[0] = tot / (float)(MM * (MM - 1));
}

__global__ void __launch_bounds__(NTHR)
k_pull(const float4* __restrict__ o4,
       const int* __restrict__ labels,
       const int* __restrict__ sub,
       const float* __restrict__ mus,
       const float* __restrict__ invw,
       float* __restrict__ pull_part,
       int n) {
    __shared__ float muL[DD * SEGS];              // 16 KB, seg-major
    __shared__ float siw[SEGS];
    __shared__ float dbuf[DEPTH][TILE_PTS * DD];  // 32 KB
    __shared__ int   labbuf[DEPTH][TILE_PTS];
    __shared__ int   subbuf[DEPTH][TILE_PTS];
    for (int i = threadIdx.x; i < DD * SEGS; i += NTHR) muL[i] = mus[i];
    for (int i = threadIdx.x; i < SEGS; i += NTHR) siw[i] = invw[i];
    __syncthreads();

    const int t    = threadIdx.x;
    const int w    = t >> 6;
    const int lane = t & 63;
    const int xm   = (t >> 1) & 3;

    float4 m0, m1, m2, m3;
    float iw = 0.0f;
    int cur = -1;
    float acc = 0.0f;

    const int nchunks = n / CHUNK_PTS;
    for (int cb = blockIdx.x; cb < nchunks; cb += gridDim.x) {
        const int pbase = cb * CHUNK_PTS;
        STAGE_TILE(0, pbase + 0 * TILE_PTS);
        STAGE_TILE(1, pbase + 1 * TILE_PTS);
        #pragma unroll
        for (int ti = 0; ti < TPB; ++ti) {
            const int bi = ti & 1;
            if (ti < TPB - 1) asm volatile("s_waitcnt vmcnt(6)" ::: "memory");
            else              asm volatile("s_waitcnt vmcnt(0)" ::: "memory");
            int lb = labbuf[bi][t];
            int sv = subbuf[bi][t];
            const float* db = &dbuf[bi][0];
            float4 a = *(const float4*)&db[((4*t + 0) ^ xm) * 4];
            float4 b = *(const float4*)&db[((4*t + 1) ^ xm) * 4];
            float4 c = *(const float4*)&db[((4*t + 2) ^ xm) * 4];
            float4 e = *(const float4*)&db[((4*t + 3) ^ xm) * 4];
            int seg = sv * MM + lb;
            if (seg != cur) {                  // once per thread, canonical
                cur = seg;
                m0 = *(const float4*)&muL[seg * DD +  0];
                m1 = *(const float4*)&muL[seg * DD +  4];
                m2 = *(const float4*)&muL[seg * DD +  8];
                m3 = *(const float4*)&muL[seg * DD + 12];
                iw = siw[seg];
            }
            float ss = a.x*a.x + a.y*a.y + a.z*a.z + a.w*a.w
                     + b.x*b.x + b.y*b.y + b.z*b.z + b.w*b.w
                     + c.x*c.x + c.y*c.y + c.z*c.z + c.w*c.w
                     + e.x*e.x + e.y*e.y + e.z*e.z + e.w*e.w;
            float rn = 1.0f / (sqrtf(ss) + NEPS);
            float dist;
            dist  = fabsf(m0.x - a.x * rn) + fabsf(m0.y - a.y * rn)
                  + fabsf(m0.z - a.z * rn) + fabsf(m0.w - a.w * rn);
            dist += fabsf(m1.x - b.x * rn) + fabsf(m1.y - b.y * rn)
                  + fabsf(m1.z - b.z * rn) + fabsf(m1.w - b.w * rn);
            dist += fabsf(m2.x - c.x * rn) + fabsf(m2.y - c.y * rn)
                  + fabsf(m2.z - c.z * rn) + fabsf(m2.w - c.w * rn);
            dist += fabsf(m3.x - e.x * rn) + fabsf(m3.y - e.y * rn)
                  + fabsf(m3.z - e.z * rn) + fabsf(m3.w - e.w * rn);
            float h = dist - DELTA_V;
            if (h > 0.0f) acc = fmaf(h * h, iw, acc);
            __builtin_amdgcn_sched_barrier(0);
            if (ti + 2 < TPB) STAGE_TILE(bi, pbase + (ti + 2) * TILE_PTS);
        }
    }
    if (blockIdx.x == 0) {
        for (int p = nchunks * CHUNK_PTS + t; p < n; p += NTHR) {
            float4 a = o4[4*p+0], b = o4[4*p+1], c = o4[4*p+2], e = o4[4*p+3];
            int seg = sub[p] * MM + labels[p];
            if (seg != cur) {
                cur = seg;
                m0 = *(const float4*)&muL[seg * DD +  0];
                m1 = *(const float4*)&muL[seg * DD +  4];
                m2 = *(const float4*)&muL[seg * DD +  8];
                m3 = *(const float4*)&muL[seg * DD + 12];
                iw = siw[seg];
            }
            float ss = a.x*a.x + a.y*a.y + a.z*a.z + a.w*a.w
                     + b.x*b.x + b.y*b.y + b.z*b.z + b.w*b.w
                     + c.x*c.x + c.y*c.y + c.z*c.z + c.w*c.w
                     + e.x*e.x + e.y*e.y + e.z*e.z + e.w*e.w;
            float rn = 1.0f / (sqrtf(ss) + NEPS);
            float dist;
            dist  = fabsf(m0.x - a.x * rn) + fabsf(m0.y - a.y * rn)
                  + fabsf(m0.z - a.z * rn) + fabsf(m0.w - a.w * rn);
            dist += fabsf(m1.x - b.x * rn) + fabsf(m1.y - b.y * rn)
                  + fabsf(m1.z - b.z * rn) + fabsf(m1.w - b.w * rn);
            dist += fabsf(m2.x - c.x * rn) + fabsf(m2.y - c.y * rn)
                  + fabsf(m2.z - c.z * rn) + fabsf(m2.w - c.w * rn);
            dist += fabsf(m3.x - e.x * rn) + fabsf(m3.y - e.y * rn)
                  + fabsf(m3.z - e.z * rn) + fabsf(m3.w - e.w * rn);
            float h = dist - DELTA_V;
            if (h > 0.0f) acc = fmaf(h * h, iw, acc);
        }
    }
    float tot = block_reduce_sum(acc);
    if (threadIdx.x == 0) pull_part[blockIdx.x] = tot;
}

__global__ void k_final(const float* __restrict__ ws, float* __restrict__ out,
                        int nblk) {
    const float* push      = ws + OFF_PUSH;
    const float* pull_part = ws + OFF_PULL;
    int t = threadIdx.x;
    float v = 0.0f;
    for (int k = t; k < nblk; k += NTHR) v += pull_part[k];
    float tot = block_reduce_sum(v);
    if (t == 0) out[0] = (tot + push[0]) * (1.0f / (float)BBATCH);
}

extern "C" void kernel_launch(void* const* d_in, const int* in_sizes, int n_in,
                              void* d_out, int out_size, void* d_ws, size_t ws_size,
                              hipStream_t stream) {
    const float* outputs = (const float*)d_in[0];
    const int* labels    = (const int*)d_in[1];
    const int* sub       = (const int*)d_in[2];
    int n = in_sizes[0] / DD;

    float* ws        = (float*)d_ws;
    float* pp        = ws + OFF_PP;
    float* mus       = ws + OFF_MUS;
    float* invw      = ws + OFF_INVW;
    float* pull_part = ws + OFF_PULL;

    int nchunks = n / CHUNK_PTS;                  // 1024 for canonical N
    int nblk = nchunks < 1 ? 1 : (nchunks > MAXBLK ? MAXBLK : nchunks);

    hipMemsetAsync(d_ws, 0, (size_t)WS_ZERO_FLOATS * sizeof(float), stream);

    k_segsum<<<nblk, NTHR, 0, stream>>>((const float4*)outputs, labels, sub,
                                        pp, n);
    k_finalize_push<<<1, NTHR, 0, stream>>>(ws);
    k_pull<<<nblk, NTHR, 0, stream>>>((const float4*)outputs, labels, sub,
                                      mus, invw, pull_part, n);
    k_final<<<1, NTHR, 0, stream>>>(ws, (float*)d_out, nblk);
}